// Round 12
// baseline (451.629 us; speedup 1.0000x reference)
//
#include <hip/hip_runtime.h>
#include <math.h>

// ---------------------------------------------------------------------------
// ws layout:
//   shorts @0: repW2 393216, repW3 @393216 (442368), repR1 @835584 (110592),
//              repR2 @946176 (110592), repP1 @1056768 (12288), repP2 @1069056
//   floats:  encb @1048576 : normalized codebook [2048,4]
//            zbuf @2097152 : projected z+bpre [16*4096, 4]  (1MB)
//            B @4194304 : conv2 out / h' [16,...]  (64x64 pair-plane)
//            A @12582912: conv1 half-out [8,...] (phase-split) -> h [16,...]
//
// Round 12: x-split the res kernels. R10/R11 counters: res pair ran at grid
//   512 = 2 blocks/CU (Occupancy 22.5%), nothing saturated -> latency-bound.
//   New block = (n, row-pair, x-half): 2 rows x 32 x, window 4 rows x 34 lx
//   (x-halo read from global), LDS 27.6KB, grid 1024 -> 4 blocks/CU. Wave =
//   (row, x-16-tile), acc[2]. Per-output limb/tap/chunk MFMA order unchanged
//   -> bit-exact. conv/scan/repack/conv1 = R11 verbatim.
// ---------------------------------------------------------------------------

typedef short v8s __attribute__((ext_vector_type(8)));
typedef float v4f __attribute__((ext_vector_type(4)));

#define B_OFF 4194304
#define A_OFF 12582912
#define ENCB_F 1048576
#define ZB_F 2097152
#define W2_S 0
#define W3_S 393216
#define WR1_S 835584
#define WR2_S 946176
#define WP1_S 1056768
#define WP2_S 1069056

// 3-limb bf16 truncation decomposition: x = h+m+l + O(2^-24 |x|)
__device__ inline void limb3(float v, unsigned short& h, unsigned short& m,
                             unsigned short& l) {
    unsigned ub = __float_as_uint(v);
    unsigned hb = ub & 0xffff0000u;
    float r1 = v - __uint_as_float(hb);
    unsigned mb = __float_as_uint(r1) & 0xffff0000u;
    float r2 = r1 - __uint_as_float(mb);
    unsigned lb = __float_as_uint(r2) & 0xffff0000u;
    h = (unsigned short)(hb >> 16);
    m = (unsigned short)(mb >> 16);
    l = (unsigned short)(lb >> 16);
}

// ----- conv configs ---------------------------------------------------------
struct CfgConv2 {   // 4x4 s2 p1 as stride-1 conv over 4 phase planes
    static constexpr int NC = 8, NT = 4, OC = 128;
    static constexpr bool RELU_IN = false, RELU_OUT = true;
    __device__ static void tap(int c, int t, int& ry, int& rx) {
        int py = (c >> 2) & 1, px = (c >> 1) & 1;
        ry = (t >> 1) - py; rx = (t & 1) - px;
    }
    __device__ static bool gaddr(int n, int oy, int r, int X, int icp, int c,
                                 int& g0, int& g1) {
        int py = (c >> 2) & 1, px = (c >> 1) & 1;
        int y2 = oy + r - 1;
        if (y2 < 0 || y2 >= 64) return false;
        int pi = (c & 1) * 16 + icp;
        g0 = (((n * 4 + py * 2 + px) * 64 + y2) * 32 + pi) * 128 + X;
        g1 = g0 + 64;
        return true;
    }
    __device__ static int widx(int c, int t, int oc, int ic) {
        int py = (c >> 2) & 1, px = (c >> 1) & 1, half = c & 1;
        int dy = 2 * (t >> 1) + (1 - py), dx = 2 * (t & 1) + (1 - px);
        return ((oc * 64 + half * 32 + ic) * 4 + dy) * 4 + dx;
    }
};
struct CfgConv3 {   // 3x3 s1 p1, 128->128
    static constexpr int NC = 4, NT = 9, OC = 128;
    static constexpr bool RELU_IN = false, RELU_OUT = false;
    __device__ static void tap(int c, int t, int& ry, int& rx) {
        ry = t / 3 - 1; rx = t % 3 - 1;
    }
    __device__ static bool gaddr(int n, int oy, int r, int X, int icp, int c,
                                 int& g0, int& g1) {
        int Yg = oy + r - 1;
        if (Yg < 0 || Yg >= 64) return false;
        int pi = c * 16 + icp;
        g0 = ((n * 64 + Yg) * 64 + pi) * 128 + X;
        g1 = g0 + 64;
        return true;
    }
    __device__ static int widx(int c, int t, int oc, int ic) {
        return ((oc * 128 + c * 32 + ic) * 3 + t / 3) * 3 + t % 3;
    }
};
struct CfgRes {     // 3x3 s1 p1, relu(in), 128->32
    static constexpr int NC = 4, NT = 9, OC = 32;
    __device__ static int widx(int c, int t, int oc, int ic) {
        return ((oc * 128 + c * 32 + ic) * 3 + t / 3) * 3 + t % 3;
    }
};
struct Cfg1x1 {     // 1x1, 32->128
    static constexpr int NC = 1, NT = 1, OC = 128;
    __device__ static int widx(int c, int t, int oc, int ic) {
        return oc * 32 + ic;
    }
};

// ----- weight repack: fp32 -> per-lane B-fragment limb layout ---------------
template <typename C>
__device__ inline void repack_one(const float* __restrict__ w,
                                  short* __restrict__ dst, int idx) {
    int s  = idx & 31;
    int oc = (idx >> 5) % C::OC;
    int ct = idx / (32 * C::OC);
    int c = ct / C::NT, t = ct % C::NT;
    float val = w[C::widx(c, t, oc, s)];
    unsigned short h, m, l;
    limb3(val, h, m, l);
    constexpr int NTILE = C::OC / 16;
    int nt = oc >> 4, o = oc & 15, q = s >> 3, j = s & 7;
    int fr = ((q * 16 + o) << 3) + j;
    dst[(((ct * 3 + 0) * NTILE + nt) << 9) + fr] = (short)h;
    dst[(((ct * 3 + 1) * NTILE + nt) << 9) + fr] = (short)m;
    dst[(((ct * 3 + 2) * NTILE + nt) << 9) + fr] = (short)l;
}

__global__ __launch_bounds__(256) void repack_all_k(
    const float* __restrict__ w2, const float* __restrict__ w3,
    const float* __restrict__ r1, const float* __restrict__ r2,
    const float* __restrict__ p1, const float* __restrict__ p2,
    const float* __restrict__ cb, short* __restrict__ base,
    float* __restrict__ encb)
{
    int idx = blockIdx.x * 256 + threadIdx.x;
    if (idx < 131072) { repack_one<CfgConv2>(w2, base + W2_S, idx); return; }
    idx -= 131072;
    if (idx < 147456) { repack_one<CfgConv3>(w3, base + W3_S, idx); return; }
    idx -= 147456;
    if (idx < 36864)  { repack_one<CfgRes>(r1, base + WR1_S, idx); return; }
    idx -= 36864;
    if (idx < 36864)  { repack_one<CfgRes>(r2, base + WR2_S, idx); return; }
    idx -= 36864;
    if (idx < 4096)   { repack_one<Cfg1x1>(p1, base + WP1_S, idx); return; }
    idx -= 4096;
    if (idx < 4096)   { repack_one<Cfg1x1>(p2, base + WP2_S, idx); return; }
    idx -= 4096;
    if (idx < 8192) {  // normalized codebook (same math as old prevq en[])
        int k = idx >> 2, d = idx & 3;
        float c0 = cb[k * 4 + 0], c1 = cb[k * 4 + 1];
        float c2 = cb[k * 4 + 2], c3 = cb[k * 4 + 3];
        float nrm = sqrtf(c0 * c0 + c1 * c1 + c2 * c2 + c3 * c3) + 1e-12f;
        encb[k * 4 + d] = cb[k * 4 + d] / nrm;
    }
}

// ----- pipelined MFMA implicit-GEMM conv (WT_M=4, WT_N=2) — R0 structure ----
template <typename C>
__global__ __launch_bounds__(256, 3) void mfma_conv(
    const float* __restrict__ in, const short* __restrict__ repw,
    const float* __restrict__ bias, float* __restrict__ out, int n0)
{
    constexpr int APLANE = 3 * 66 * 32;        // shorts; dwords 3168
    constexpr int NTILE  = C::OC / 16;
    __shared__ __align__(16) short lA[3 * APLANE];

    int tid = threadIdx.x;
    int lane = tid & 63, wv = tid >> 6;
    int n_img = blockIdx.x >> 6, oy = blockIdx.x & 63;

    // zero halo cells (col 0 and 65, all rows, all limbs)
    for (int idx = tid; idx < 3 * 3 * 2 * 16; idx += 256) {
        int plane = idx / 96;
        int rem = idx % 96;
        int rr = rem / 32;
        int hc = (rem / 16) & 1;
        int d = idx & 15;
        ((unsigned*)lA)[plane * 3168 + (rr * 66 + hc * 65) * 16 + d] = 0;
    }

    v4f acc[4][2] = {};
    int nbase = wv * 2;
    int Xq = tid & 15, icp = tid >> 4, quad = lane >> 4;

    float pv[24];
    auto issue_loads = [&](int c) {
#pragma unroll
        for (int it = 0; it < 12; it++) {
            int r = it >> 2, xg = it & 3;
            int X = xg * 16 + Xq;
            int g0, g1;
            float v0 = 0.f, v1 = 0.f;
            if (C::gaddr(n_img, oy, r, X, icp, c, g0, g1)) {
                v0 = in[g0];
                v1 = in[g1];
            }
            pv[2 * it] = v0; pv[2 * it + 1] = v1;
        }
    };
    auto load_bf = [&](int c, int t, v8s (&dst)[2][3]) {
#pragma unroll
        for (int nt = 0; nt < 2; nt++)
#pragma unroll
            for (int L = 0; L < 3; L++)
                dst[nt][L] = *(const v8s*)(repw +
                    ((((c * C::NT + t) * 3 + L) * NTILE + (nbase + nt)) << 9) +
                    (lane << 3));
    };

    issue_loads(0);

    for (int c = 0; c < C::NC; c++) {
        __syncthreads();   // prev chunk's readers done before lA overwrite
#pragma unroll
        for (int it = 0; it < 12; it++) {
            int r = it >> 2, xg = it & 3;
            int X = xg * 16 + Xq;
            float v0 = pv[2 * it], v1 = pv[2 * it + 1];
            if constexpr (C::RELU_IN) { v0 = fmaxf(v0, 0.f); v1 = fmaxf(v1, 0.f); }
            unsigned short h0, m0, l0, h1, m1, l1;
            limb3(v0, h0, m0, l0);
            limb3(v1, h1, m1, l1);
            int cell = r * 66 + X + 1;
            int f = (cell + (cell >> 2)) & 3;
            int phys = (icp & 3) + 4 * (((icp >> 2) + f) & 3);
            unsigned* pa = (unsigned*)lA + cell * 16 + phys;
            pa[0]        = (unsigned)h0 | ((unsigned)h1 << 16);
            pa[3168]     = (unsigned)m0 | ((unsigned)m1 << 16);
            pa[2 * 3168] = (unsigned)l0 | ((unsigned)l1 << 16);
        }
        __syncthreads();   // lA staged
        if (c + 1 < C::NC) issue_loads(c + 1);   // prefetch next chunk

        v8s bf[2][2][3];
        load_bf(c, 0, bf[0]);
#pragma unroll
        for (int t = 0; t < C::NT; t++) {
            constexpr int NTT = C::NT;
            if (t + 1 < NTT) load_bf(c, t + 1, bf[(t + 1) & 1]);
            int ry, rx;
            C::tap(c, t, ry, rx);
#pragma unroll
            for (int mt = 0; mt < 4; mt++) {
                int x = mt * 16 + (lane & 15);
                int cell = (ry + 1) * 66 + (x + rx + 1);
                int f = (cell + (cell >> 2)) & 3;
                int aa = cell * 32 + (((quad + f) & 3) << 3);
                v8s ah = *(const v8s*)&lA[aa];
                v8s am = *(const v8s*)&lA[APLANE + aa];
                v8s al = *(const v8s*)&lA[2 * APLANE + aa];
#pragma unroll
                for (int nt = 0; nt < 2; nt++) {
                    v4f a0 = acc[mt][nt];
                    a0 = __builtin_amdgcn_mfma_f32_16x16x32_bf16(ah, bf[t & 1][nt][0], a0, 0, 0, 0);
                    a0 = __builtin_amdgcn_mfma_f32_16x16x32_bf16(ah, bf[t & 1][nt][1], a0, 0, 0, 0);
                    a0 = __builtin_amdgcn_mfma_f32_16x16x32_bf16(am, bf[t & 1][nt][0], a0, 0, 0, 0);
                    a0 = __builtin_amdgcn_mfma_f32_16x16x32_bf16(am, bf[t & 1][nt][1], a0, 0, 0, 0);
                    a0 = __builtin_amdgcn_mfma_f32_16x16x32_bf16(ah, bf[t & 1][nt][2], a0, 0, 0, 0);
                    a0 = __builtin_amdgcn_mfma_f32_16x16x32_bf16(al, bf[t & 1][nt][0], a0, 0, 0, 0);
                    acc[mt][nt] = a0;
                }
            }
        }
    }
    // ---- epilogue: pair-plane store, col=lane&15 (oc), row=quad*4+reg (x) --
#pragma unroll
    for (int mt = 0; mt < 4; mt++) {
        int x0 = mt * 16 + quad * 4;
#pragma unroll
        for (int nt = 0; nt < 2; nt++) {
            int oc = (nbase + nt) * 16 + (lane & 15);
            float bv = bias[oc];
            float v0 = acc[mt][nt][0] + bv;
            float v1 = acc[mt][nt][1] + bv;
            float v2 = acc[mt][nt][2] + bv;
            float v3 = acc[mt][nt][3] + bv;
            if constexpr (C::RELU_OUT) {
                v0 = fmaxf(v0, 0.f); v1 = fmaxf(v1, 0.f);
                v2 = fmaxf(v2, 0.f); v3 = fmaxf(v3, 0.f);
            }
            float4 o = make_float4(v0, v1, v2, v3);
            int off = (((n0 + n_img) * 64 + oy) * 64 + (oc >> 1)) * 128 +
                      (oc & 1) * 64 + x0;
            *(float4*)&out[off] = o;
        }
    }
}

// ----- residual block, x-split: 2 rows x 32 x per block (grid 1024) ---------
// wave (jrow, xhw) owns row jrow, x-16-tile xhw. acc[2] (nt). Window 4 rows x
// 34 lx (x-halo from global). Per-output MFMA order identical to R11.
__global__ __launch_bounds__(256, 4) void mfma_res(
    const float* __restrict__ in, const short* __restrict__ repw,
    const float* __restrict__ b1, const short* __restrict__ repp,
    const float* __restrict__ b2, float* __restrict__ out)
{
    constexpr int PLANE_D = 4 * 36 * 16;   // 2304 dwords per limb plane
    constexpr int PLANE_S = 2 * PLANE_D;   // 4608 shorts
    __shared__ __align__(16) short lA[3 * PLANE_S];   // 27648 B

    int tid = threadIdx.x;
    int lane = tid & 63, wv = tid >> 6;
    int n_img = blockIdx.x >> 6;
    int sub = blockIdx.x & 63;
    int oy0 = (sub >> 1) << 1;
    int xh2 = sub & 1;
    int jrow = wv >> 1, xhw = wv & 1;

    v4f acc[2] = {};
    int Xq = tid & 15, icp = tid >> 4, quad = lane >> 4;

    float pv[24];
    auto issue_loads = [&](int c) {
#pragma unroll
        for (int it = 0; it < 12; it++) {
            int r = it / 3, xg = it % 3;
            int lx = xg * 16 + Xq;
            int Xg = xh2 * 32 + lx - 1;
            int Yg = oy0 + r - 1;
            float v0 = 0.f, v1 = 0.f;
            if (Yg >= 0 && Yg < 64 && Xg >= 0 && Xg < 64) {
                int g = ((n_img * 64 + Yg) * 64 + (c * 16 + icp)) * 128 + Xg;
                v0 = in[g];
                v1 = in[g + 64];
            }
            pv[2 * it] = v0; pv[2 * it + 1] = v1;
        }
    };

    issue_loads(0);

    for (int c = 0; c < 4; c++) {
        __syncthreads();
#pragma unroll
        for (int it = 0; it < 12; it++) {
            int r = it / 3, xg = it % 3;
            int lx = xg * 16 + Xq;
            float v0 = fmaxf(pv[2 * it], 0.f);       // relu(h)
            float v1 = fmaxf(pv[2 * it + 1], 0.f);
            unsigned short h0, m0, l0, h1, m1, l1;
            limb3(v0, h0, m0, l0);
            limb3(v1, h1, m1, l1);
            if (lx < 34) {
                int cell = r * 36 + lx;
                int f = (cell + (cell >> 2)) & 3;
                int phys = (icp & 3) + 4 * (((icp >> 2) + f) & 3);
                unsigned* pa = (unsigned*)lA + cell * 16 + phys;
                pa[0]           = (unsigned)h0 | ((unsigned)h1 << 16);
                pa[PLANE_D]     = (unsigned)m0 | ((unsigned)m1 << 16);
                pa[2 * PLANE_D] = (unsigned)l0 | ((unsigned)l1 << 16);
            }
        }
        __syncthreads();
        if (c + 1 < 4) issue_loads(c + 1);

        v8s bf[2][2][3];
        auto load_bf = [&](int t, v8s (&dst)[2][3]) {
#pragma unroll
            for (int nt = 0; nt < 2; nt++)
#pragma unroll
                for (int L = 0; L < 3; L++)
                    dst[nt][L] = *(const v8s*)(repw +
                        ((((c * 9 + t) * 3 + L) * 2 + nt) << 9) + (lane << 3));
        };
        load_bf(0, bf[0]);
#pragma unroll
        for (int t = 0; t < 9; t++) {
            if (t + 1 < 9) load_bf(t + 1, bf[(t + 1) & 1]);
            int ry = t / 3 - 1, rx = t % 3 - 1;
            int lxw = xhw * 16 + (lane & 15);
            int cell = (jrow + ry + 1) * 36 + (lxw + rx + 1);
            int f = (cell + (cell >> 2)) & 3;
            int aa = cell * 32 + (((quad + f) & 3) << 3);
            v8s ah = *(const v8s*)&lA[aa];
            v8s am = *(const v8s*)&lA[PLANE_S + aa];
            v8s al = *(const v8s*)&lA[2 * PLANE_S + aa];
#pragma unroll
            for (int nt = 0; nt < 2; nt++) {
                v4f a0 = acc[nt];
                a0 = __builtin_amdgcn_mfma_f32_16x16x32_bf16(ah, bf[t & 1][nt][0], a0, 0, 0, 0);
                a0 = __builtin_amdgcn_mfma_f32_16x16x32_bf16(ah, bf[t & 1][nt][1], a0, 0, 0, 0);
                a0 = __builtin_amdgcn_mfma_f32_16x16x32_bf16(am, bf[t & 1][nt][0], a0, 0, 0, 0);
                a0 = __builtin_amdgcn_mfma_f32_16x16x32_bf16(am, bf[t & 1][nt][1], a0, 0, 0, 0);
                a0 = __builtin_amdgcn_mfma_f32_16x16x32_bf16(ah, bf[t & 1][nt][2], a0, 0, 0, 0);
                a0 = __builtin_amdgcn_mfma_f32_16x16x32_bf16(al, bf[t & 1][nt][0], a0, 0, 0, 0);
                acc[nt] = a0;
            }
        }
    }

    // ===== stage 2: relu(t+b1) limbs -> LDS; per-row 32-x regions =====
    __syncthreads();
#pragma unroll
    for (int nt = 0; nt < 2; nt++) {
        int ic = nt * 16 + (lane & 15);
        int icp2 = ic >> 1, hilo = ic & 1;
        float bv = b1[ic];
#pragma unroll
        for (int r = 0; r < 4; r++) {
            int xr = xhw * 16 + quad * 4 + r;
            float v = fmaxf(acc[nt][r] + bv, 0.f);
            unsigned short h, m, l;
            limb3(v, h, m, l);
            int f = (xr + (xr >> 2)) & 3;
            int phys = (icp2 & 3) + 4 * (((icp2 >> 2) + f) & 3);
            int sa = xr * 32 + phys * 2 + hilo;
            lA[jrow * 1024 + sa]        = (short)h;
            lA[2048 + jrow * 1024 + sa] = (short)m;
            lA[4096 + jrow * 1024 + sa] = (short)l;
        }
    }
    __syncthreads();

    // GEMM-2: wave (jrow,xhw): M=16 x-tile, N=128 (nt 0..7), K=32
    v4f a2[8] = {};
    {
        int xr = xhw * 16 + (lane & 15);
        int f = (xr + (xr >> 2)) & 3;
        int aa = xr * 32 + (((quad + f) & 3) << 3);
        v8s ah = *(const v8s*)&lA[jrow * 1024 + aa];
        v8s am = *(const v8s*)&lA[2048 + jrow * 1024 + aa];
        v8s al = *(const v8s*)&lA[4096 + jrow * 1024 + aa];
#pragma unroll
        for (int nt = 0; nt < 8; nt++) {
            v8s bh = *(const v8s*)(repp + ((0 * 8 + nt) << 9) + (lane << 3));
            v8s bm = *(const v8s*)(repp + ((1 * 8 + nt) << 9) + (lane << 3));
            v8s bl = *(const v8s*)(repp + ((2 * 8 + nt) << 9) + (lane << 3));
            v4f a0 = a2[nt];
            a0 = __builtin_amdgcn_mfma_f32_16x16x32_bf16(ah, bh, a0, 0, 0, 0);
            a0 = __builtin_amdgcn_mfma_f32_16x16x32_bf16(ah, bm, a0, 0, 0, 0);
            a0 = __builtin_amdgcn_mfma_f32_16x16x32_bf16(am, bh, a0, 0, 0, 0);
            a0 = __builtin_amdgcn_mfma_f32_16x16x32_bf16(am, bm, a0, 0, 0, 0);
            a0 = __builtin_amdgcn_mfma_f32_16x16x32_bf16(ah, bl, a0, 0, 0, 0);
            a0 = __builtin_amdgcn_mfma_f32_16x16x32_bf16(al, bh, a0, 0, 0, 0);
            a2[nt] = a0;
        }
    }
    // epilogue: out = h + t2 + b2   (pair-plane layout)
#pragma unroll
    for (int nt = 0; nt < 8; nt++) {
        int oc = nt * 16 + (lane & 15);
        int x0 = xh2 * 32 + xhw * 16 + quad * 4;
        int off = ((n_img * 64 + (oy0 + jrow)) * 64 + (oc >> 1)) * 128 +
                  (oc & 1) * 64 + x0;
        float4 hv = *(const float4*)&in[off];
        float bv = b2[oc];
        float4 o = make_float4(hv.x + a2[nt][0] + bv, hv.y + a2[nt][1] + bv,
                               hv.z + a2[nt][2] + bv, hv.w + a2[nt][3] + bv);
        *(float4*)&out[off] = o;
    }
}

// ----- fused res2 + 1x1 projection, x-split; writes z+bpre to zbuf ----------
__global__ __launch_bounds__(256, 4) void mfma_res_vq(
    const float* __restrict__ in, const short* __restrict__ repw,
    const float* __restrict__ b1, const short* __restrict__ repp,
    const float* __restrict__ b2, const float* __restrict__ wpre,
    const float* __restrict__ bpre, float* __restrict__ zbuf)
{
    constexpr int PLANE_D = 4 * 36 * 16;
    constexpr int PLANE_S = 2 * PLANE_D;
    __shared__ __align__(16) short lA[3 * PLANE_S];   // 27648 B

    int tid = threadIdx.x;
    int lane = tid & 63, wv = tid >> 6;
    int n_img = blockIdx.x >> 6;
    int sub = blockIdx.x & 63;
    int oy0 = (sub >> 1) << 1;
    int xh2 = sub & 1;
    int jrow = wv >> 1, xhw = wv & 1;

    v4f acc[2] = {};
    int Xq = tid & 15, icp = tid >> 4, quad = lane >> 4;

    float pv[24];
    auto issue_loads = [&](int c) {
#pragma unroll
        for (int it = 0; it < 12; it++) {
            int r = it / 3, xg = it % 3;
            int lx = xg * 16 + Xq;
            int Xg = xh2 * 32 + lx - 1;
            int Yg = oy0 + r - 1;
            float v0 = 0.f, v1 = 0.f;
            if (Yg >= 0 && Yg < 64 && Xg >= 0 && Xg < 64) {
                int g = ((n_img * 64 + Yg) * 64 + (c * 16 + icp)) * 128 + Xg;
                v0 = in[g];
                v1 = in[g + 64];
            }
            pv[2 * it] = v0; pv[2 * it + 1] = v1;
        }
    };

    issue_loads(0);

    for (int c = 0; c < 4; c++) {
        __syncthreads();
#pragma unroll
        for (int it = 0; it < 12; it++) {
            int r = it / 3, xg = it % 3;
            int lx = xg * 16 + Xq;
            float v0 = fmaxf(pv[2 * it], 0.f);
            float v1 = fmaxf(pv[2 * it + 1], 0.f);
            unsigned short h0, m0, l0, h1, m1, l1;
            limb3(v0, h0, m0, l0);
            limb3(v1, h1, m1, l1);
            if (lx < 34) {
                int cell = r * 36 + lx;
                int f = (cell + (cell >> 2)) & 3;
                int phys = (icp & 3) + 4 * (((icp >> 2) + f) & 3);
                unsigned* pa = (unsigned*)lA + cell * 16 + phys;
                pa[0]           = (unsigned)h0 | ((unsigned)h1 << 16);
                pa[PLANE_D]     = (unsigned)m0 | ((unsigned)m1 << 16);
                pa[2 * PLANE_D] = (unsigned)l0 | ((unsigned)l1 << 16);
            }
        }
        __syncthreads();
        if (c + 1 < 4) issue_loads(c + 1);

        v8s bf[2][2][3];
        auto load_bf = [&](int t, v8s (&dst)[2][3]) {
#pragma unroll
            for (int nt = 0; nt < 2; nt++)
#pragma unroll
                for (int L = 0; L < 3; L++)
                    dst[nt][L] = *(const v8s*)(repw +
                        ((((c * 9 + t) * 3 + L) * 2 + nt) << 9) + (lane << 3));
        };
        load_bf(0, bf[0]);
#pragma unroll
        for (int t = 0; t < 9; t++) {
            if (t + 1 < 9) load_bf(t + 1, bf[(t + 1) & 1]);
            int ry = t / 3 - 1, rx = t % 3 - 1;
            int lxw = xhw * 16 + (lane & 15);
            int cell = (jrow + ry + 1) * 36 + (lxw + rx + 1);
            int f = (cell + (cell >> 2)) & 3;
            int aa = cell * 32 + (((quad + f) & 3) << 3);
            v8s ah = *(const v8s*)&lA[aa];
            v8s am = *(const v8s*)&lA[PLANE_S + aa];
            v8s al = *(const v8s*)&lA[2 * PLANE_S + aa];
#pragma unroll
            for (int nt = 0; nt < 2; nt++) {
                v4f a0 = acc[nt];
                a0 = __builtin_amdgcn_mfma_f32_16x16x32_bf16(ah, bf[t & 1][nt][0], a0, 0, 0, 0);
                a0 = __builtin_amdgcn_mfma_f32_16x16x32_bf16(ah, bf[t & 1][nt][1], a0, 0, 0, 0);
                a0 = __builtin_amdgcn_mfma_f32_16x16x32_bf16(am, bf[t & 1][nt][0], a0, 0, 0, 0);
                a0 = __builtin_amdgcn_mfma_f32_16x16x32_bf16(am, bf[t & 1][nt][1], a0, 0, 0, 0);
                a0 = __builtin_amdgcn_mfma_f32_16x16x32_bf16(ah, bf[t & 1][nt][2], a0, 0, 0, 0);
                a0 = __builtin_amdgcn_mfma_f32_16x16x32_bf16(al, bf[t & 1][nt][0], a0, 0, 0, 0);
                acc[nt] = a0;
            }
        }
    }

    // ===== stage 2: relu(t+b1) limbs -> LDS; per-row 32-x regions =====
    __syncthreads();
#pragma unroll
    for (int nt = 0; nt < 2; nt++) {
        int ic = nt * 16 + (lane & 15);
        int icp2 = ic >> 1, hilo = ic & 1;
        float bv = b1[ic];
#pragma unroll
        for (int r = 0; r < 4; r++) {
            int xr = xhw * 16 + quad * 4 + r;
            float v = fmaxf(acc[nt][r] + bv, 0.f);
            unsigned short h, m, l;
            limb3(v, h, m, l);
            int f = (xr + (xr >> 2)) & 3;
            int phys = (icp2 & 3) + 4 * (((icp2 >> 2) + f) & 3);
            int sa = xr * 32 + phys * 2 + hilo;
            lA[jrow * 1024 + sa]        = (short)h;
            lA[2048 + jrow * 1024 + sa] = (short)m;
            lA[4096 + jrow * 1024 + sa] = (short)l;
        }
    }
    __syncthreads();

    // per-thread wpre cache: wp[nt][d] = wpre[d*128 + nt*16 + lane15]
    float wp[8][4];
#pragma unroll
    for (int nt = 0; nt < 8; nt++)
#pragma unroll
        for (int d = 0; d < 4; d++)
            wp[nt][d] = wpre[d * 128 + nt * 16 + (lane & 15)];

    // GEMM-2 + z accumulation; butterfly; write z+bpre to zbuf
    v4f a2[8] = {};
    {
        int xr = xhw * 16 + (lane & 15);
        int f = (xr + (xr >> 2)) & 3;
        int aa = xr * 32 + (((quad + f) & 3) << 3);
        v8s ah = *(const v8s*)&lA[jrow * 1024 + aa];
        v8s am = *(const v8s*)&lA[2048 + jrow * 1024 + aa];
        v8s al = *(const v8s*)&lA[4096 + jrow * 1024 + aa];
#pragma unroll
        for (int nt = 0; nt < 8; nt++) {
            v8s bh = *(const v8s*)(repp + ((0 * 8 + nt) << 9) + (lane << 3));
            v8s bm = *(const v8s*)(repp + ((1 * 8 + nt) << 9) + (lane << 3));
            v8s bl = *(const v8s*)(repp + ((2 * 8 + nt) << 9) + (lane << 3));
            v4f a0 = a2[nt];
            a0 = __builtin_amdgcn_mfma_f32_16x16x32_bf16(ah, bh, a0, 0, 0, 0);
            a0 = __builtin_amdgcn_mfma_f32_16x16x32_bf16(ah, bm, a0, 0, 0, 0);
            a0 = __builtin_amdgcn_mfma_f32_16x16x32_bf16(am, bh, a0, 0, 0, 0);
            a0 = __builtin_amdgcn_mfma_f32_16x16x32_bf16(am, bm, a0, 0, 0, 0);
            a0 = __builtin_amdgcn_mfma_f32_16x16x32_bf16(ah, bl, a0, 0, 0, 0);
            a0 = __builtin_amdgcn_mfma_f32_16x16x32_bf16(al, bh, a0, 0, 0, 0);
            a2[nt] = a0;
        }
    }
    // h' = h + t2 + b2 stays in registers; accumulate partial z
    float z[4][4];   // [r][d], compile-time indexed only
#pragma unroll
    for (int r = 0; r < 4; r++)
#pragma unroll
        for (int d = 0; d < 4; d++) z[r][d] = 0.f;
#pragma unroll
    for (int nt = 0; nt < 8; nt++) {
        int oc = nt * 16 + (lane & 15);
        int x0 = xh2 * 32 + xhw * 16 + quad * 4;
        int off = ((n_img * 64 + (oy0 + jrow)) * 64 + (oc >> 1)) * 128 +
                  (oc & 1) * 64 + x0;
        float4 hv = *(const float4*)&in[off];
        float bv = b2[oc];
        float o0 = fmaxf(hv.x + a2[nt][0] + bv, 0.f);
        float o1 = fmaxf(hv.y + a2[nt][1] + bv, 0.f);
        float o2 = fmaxf(hv.z + a2[nt][2] + bv, 0.f);
        float o3 = fmaxf(hv.w + a2[nt][3] + bv, 0.f);
#pragma unroll
        for (int d = 0; d < 4; d++) {
            z[0][d] = fmaf(o0, wp[nt][d], z[0][d]);
            z[1][d] = fmaf(o1, wp[nt][d], z[1][d]);
            z[2][d] = fmaf(o2, wp[nt][d], z[2][d]);
            z[3][d] = fmaf(o3, wp[nt][d], z[3][d]);
        }
    }
    // butterfly over the 16 lanes of this quad group (channels)
#pragma unroll
    for (int mask = 1; mask < 16; mask <<= 1)
#pragma unroll
        for (int r = 0; r < 4; r++)
#pragma unroll
            for (int d = 0; d < 4; d++)
                z[r][d] += __shfl_xor(z[r][d], mask);
    // lane l15==r*4+d writes position (xglobal), dim d -> coalesced
    {
        int l15 = lane & 15;
#pragma unroll
        for (int r = 0; r < 4; r++)
#pragma unroll
            for (int d = 0; d < 4; d++)
                if (l15 == r * 4 + d) {
                    int xg0 = xh2 * 32 + xhw * 16 + quad * 4 + r;
                    zbuf[(((n_img * 64 + oy0 + jrow) * 64) + xg0) * 4 + d]
                        = z[r][d] + bpre[d];
                }
    }
}

// ----- standalone argmax scan: codebook in LDS, wave-uniform k --------------
__global__ __launch_bounds__(256) void scan_vq(
    const float* __restrict__ zbuf, const float* __restrict__ encb,
    const float* __restrict__ cb, float* __restrict__ out)
{
    __shared__ __align__(16) float en[2048 * 4];
    __shared__ float cwS[4][64];
    __shared__ int   cwI[4][64];
    for (int i = threadIdx.x; i < 2048; i += 256)
        ((float4*)en)[i] = ((const float4*)encb)[i];
    __syncthreads();

    int lane = threadIdx.x & 63, w = threadIdx.x >> 6;
    int gpos = blockIdx.x * 64 + lane;
    float4 zv = ((const float4*)zbuf)[gpos];

    int kb = w * 512;
    float b0 = -1e30f, b1 = -1e30f, b2 = -1e30f, b3 = -1e30f;
    int i0 = kb, i1 = kb + 1, i2 = kb + 2, i3 = kb + 3;
    for (int i = 0; i < 512; i += 4) {
        float4 e0 = ((const float4*)en)[kb + i];
        float4 e1 = ((const float4*)en)[kb + i + 1];
        float4 e2 = ((const float4*)en)[kb + i + 2];
        float4 e3 = ((const float4*)en)[kb + i + 3];
        float s0 = zv.x * e0.x + zv.y * e0.y + zv.z * e0.z + zv.w * e0.w;
        float s1 = zv.x * e1.x + zv.y * e1.y + zv.z * e1.z + zv.w * e1.w;
        float s2 = zv.x * e2.x + zv.y * e2.y + zv.z * e2.z + zv.w * e2.w;
        float s3 = zv.x * e3.x + zv.y * e3.y + zv.z * e3.z + zv.w * e3.w;
        if (s0 > b0) { b0 = s0; i0 = kb + i; }
        if (s1 > b1) { b1 = s1; i1 = kb + i + 1; }
        if (s2 > b2) { b2 = s2; i2 = kb + i + 2; }
        if (s3 > b3) { b3 = s3; i3 = kb + i + 3; }
    }
    float best = b0; int bidx = i0;
    if (b1 > best || (b1 == best && i1 < bidx)) { best = b1; bidx = i1; }
    if (b2 > best || (b2 == best && i2 < bidx)) { best = b2; bidx = i2; }
    if (b3 > best || (b3 == best && i3 < bidx)) { best = b3; bidx = i3; }
    cwS[w][lane] = best;
    cwI[w][lane] = bidx;
    __syncthreads();
    if (w == 0) {
#pragma unroll
        for (int ww = 1; ww < 4; ww++) {
            float ob = cwS[ww][lane];
            int   oi = cwI[ww][lane];
            if (ob > best || (ob == best && oi < bidx)) { best = ob; bidx = oi; }
        }
        int n = gpos >> 12, pos = gpos & 4095;
#pragma unroll
        for (int d = 0; d < 4; d++)
            out[(n * 4 + d) * 4096 + pos] = cb[bidx * 4 + d];
    }
}

// ----- conv1: [8,1,256,256] -> phase-split pair-plane, relu (fp32) ----------
__global__ __launch_bounds__(256) void conv1_k(
    const float* __restrict__ x, const float* __restrict__ w,
    const float* __restrict__ b, float* __restrict__ out)
{
    int tid = blockIdx.x * 256 + threadIdx.x;     // 131072
    int n   = tid >> 14;
    int rem = tid & 16383;
    int oy  = rem >> 7;
    int ox  = rem & 127;
    int iy0 = oy * 2 - 1, ix0 = ox * 2 - 1;
    const float* xb = x + n * 65536;
    float v[16];
#pragma unroll
    for (int ky = 0; ky < 4; ky++) {
#pragma unroll
        for (int kx = 0; kx < 4; kx++) {
            int iy = iy0 + ky, ix = ix0 + kx;
            bool ok = (iy >= 0) & (iy < 256) & (ix >= 0) & (ix < 256);
            v[ky * 4 + kx] = ok ? xb[iy * 256 + ix] : 0.f;
        }
    }
    int py = oy & 1, y2 = oy >> 1, px = ox & 1, x2 = ox >> 1;
    int obase = (((n * 4 + py * 2 + px) * 64 + y2) * 32) * 128 + x2;
    for (int oc = 0; oc < 64; oc++) {
        float acc = b[oc];
        const float* wp = w + oc * 16;
#pragma unroll
        for (int k = 0; k < 16; k++) acc = fmaf(v[k], wp[k], acc);
        out[obase + (oc >> 1) * 128 + (oc & 1) * 64] = fmaxf(acc, 0.f);
    }
}

extern "C" void kernel_launch(void* const* d_in, const int* in_sizes, int n_in,
                              void* d_out, int out_size, void* d_ws, size_t ws_size,
                              hipStream_t stream)
{
    const float* x    = (const float*)d_in[0];
    const float* w1   = (const float*)d_in[1];
    const float* b1   = (const float*)d_in[2];
    const float* w2   = (const float*)d_in[3];
    const float* b2   = (const float*)d_in[4];
    const float* w3   = (const float*)d_in[5];
    const float* b3   = (const float*)d_in[6];
    const float* r1w1 = (const float*)d_in[7];
    const float* r1b1 = (const float*)d_in[8];
    const float* r1w2 = (const float*)d_in[9];
    const float* r1b2 = (const float*)d_in[10];
    const float* r2w1 = (const float*)d_in[11];
    const float* r2b1 = (const float*)d_in[12];
    const float* r2w2 = (const float*)d_in[13];
    const float* r2b2 = (const float*)d_in[14];
    const float* wpre = (const float*)d_in[15];
    const float* bpre = (const float*)d_in[16];
    const float* cb   = (const float*)d_in[17];
    float* out = (float*)d_out;

    float* ws   = (float*)d_ws;
    short* wsS  = (short*)d_ws;
    float* encb = ws + ENCB_F;
    float* zbuf = ws + ZB_F;
    float* B = ws + B_OFF;
    float* A = ws + A_OFF;

    // merged repack for all 6 weight tensors + normalized codebook
    repack_all_k<<<1440, 256, 0, stream>>>(w2, w3, r1w1, r2w1, r1w2, r2w2,
                                           cb, wsS, encb);

    // front end, batch split in halves ping-ponging through A
    conv1_k<<<512, 256, 0, stream>>>(x,               w1, b1, A);
    mfma_conv<CfgConv2><<<512, 256, 0, stream>>>(A, wsS + W2_S, b2, B, 0);
    conv1_k<<<512, 256, 0, stream>>>(x + 8 * 65536,   w1, b1, A);
    mfma_conv<CfgConv2><<<512, 256, 0, stream>>>(A, wsS + W2_S, b2, B, 8);

    // conv3: B -> h @ A
    mfma_conv<CfgConv3><<<1024, 256, 0, stream>>>(B, wsS + W3_S, b3, A, 0);

    // res1: A -> B  (x-split, grid 1024)
    mfma_res<<<1024, 256, 0, stream>>>(A, wsS + WR1_S, r1b1, wsS + WP1_S, r1b2, B);
    // res2 + projection fused: B -> zbuf  (x-split, grid 1024)
    mfma_res_vq<<<1024, 256, 0, stream>>>(B, wsS + WR2_S, r2b1, wsS + WP2_S,
                                          r2b2, wpre, bpre, zbuf);
    // argmax scan: zbuf (1MB) + LDS codebook -> out
    scan_vq<<<1024, 256, 0, stream>>>(zbuf, encb, cb, out);
}

// Round 13
// 423.968 us; speedup vs baseline: 1.0652x; 1.0652x over previous
//
#include <hip/hip_runtime.h>
#include <math.h>

// ---------------------------------------------------------------------------
// ws layout:
//   shorts @0: repW2 393216, repW3 @393216 (442368), repR1 @835584 (110592),
//              repR2 @946176 (110592), repP1 @1056768 (12288), repP2 @1069056
//   floats:  encb @1048576 : normalized codebook [2048,4]
//            zbuf @2097152 : projected z+bpre [16*4096, 4]  (1MB)
//            B @4194304 : conv2 out / h' [16,...]  (64x64 pair-plane)
//            A @12582912: conv1 half-out [8,...] (phase-split) -> h [16,...]
//
// Round 13 == revert to round-11 best (428.7us). R12's x-split of the res
//   kernels regressed (451.6): per-output staging x1.5, B-loads x2, halo
//   re-loads outweighed the occupancy gain. Third confirmation that this
//   kernel family is work-efficiency-dominated, not schedule-dominated.
//   Pipeline: conv1 (phase-split pair-plane) -> conv2 (unit-stride staging)
//   -> conv3 -> res1 -> res2+projection fused (h' never hits HBM; z 1MB)
//   -> scan_vq (codebook in LDS, wave-uniform k, exact first-max).
// ---------------------------------------------------------------------------

typedef short v8s __attribute__((ext_vector_type(8)));
typedef float v4f __attribute__((ext_vector_type(4)));

#define B_OFF 4194304
#define A_OFF 12582912
#define ENCB_F 1048576
#define ZB_F 2097152
#define W2_S 0
#define W3_S 393216
#define WR1_S 835584
#define WR2_S 946176
#define WP1_S 1056768
#define WP2_S 1069056

// 3-limb bf16 truncation decomposition: x = h+m+l + O(2^-24 |x|)
__device__ inline void limb3(float v, unsigned short& h, unsigned short& m,
                             unsigned short& l) {
    unsigned ub = __float_as_uint(v);
    unsigned hb = ub & 0xffff0000u;
    float r1 = v - __uint_as_float(hb);
    unsigned mb = __float_as_uint(r1) & 0xffff0000u;
    float r2 = r1 - __uint_as_float(mb);
    unsigned lb = __float_as_uint(r2) & 0xffff0000u;
    h = (unsigned short)(hb >> 16);
    m = (unsigned short)(mb >> 16);
    l = (unsigned short)(lb >> 16);
}

// ----- conv configs ---------------------------------------------------------
struct CfgConv2 {   // 4x4 s2 p1 as stride-1 conv over 4 phase planes
    static constexpr int NC = 8, NT = 4, OC = 128;
    static constexpr bool RELU_IN = false, RELU_OUT = true;
    __device__ static void tap(int c, int t, int& ry, int& rx) {
        int py = (c >> 2) & 1, px = (c >> 1) & 1;
        ry = (t >> 1) - py; rx = (t & 1) - px;
    }
    __device__ static bool gaddr(int n, int oy, int r, int X, int icp, int c,
                                 int& g0, int& g1) {
        int py = (c >> 2) & 1, px = (c >> 1) & 1;
        int y2 = oy + r - 1;
        if (y2 < 0 || y2 >= 64) return false;
        int pi = (c & 1) * 16 + icp;
        g0 = (((n * 4 + py * 2 + px) * 64 + y2) * 32 + pi) * 128 + X;
        g1 = g0 + 64;
        return true;
    }
    __device__ static int widx(int c, int t, int oc, int ic) {
        int py = (c >> 2) & 1, px = (c >> 1) & 1, half = c & 1;
        int dy = 2 * (t >> 1) + (1 - py), dx = 2 * (t & 1) + (1 - px);
        return ((oc * 64 + half * 32 + ic) * 4 + dy) * 4 + dx;
    }
};
struct CfgConv3 {   // 3x3 s1 p1, 128->128
    static constexpr int NC = 4, NT = 9, OC = 128;
    static constexpr bool RELU_IN = false, RELU_OUT = false;
    __device__ static void tap(int c, int t, int& ry, int& rx) {
        ry = t / 3 - 1; rx = t % 3 - 1;
    }
    __device__ static bool gaddr(int n, int oy, int r, int X, int icp, int c,
                                 int& g0, int& g1) {
        int Yg = oy + r - 1;
        if (Yg < 0 || Yg >= 64) return false;
        int pi = c * 16 + icp;
        g0 = ((n * 64 + Yg) * 64 + pi) * 128 + X;
        g1 = g0 + 64;
        return true;
    }
    __device__ static int widx(int c, int t, int oc, int ic) {
        return ((oc * 128 + c * 32 + ic) * 3 + t / 3) * 3 + t % 3;
    }
};
struct CfgRes {     // 3x3 s1 p1, relu(in), 128->32
    static constexpr int NC = 4, NT = 9, OC = 32;
    __device__ static int widx(int c, int t, int oc, int ic) {
        return ((oc * 128 + c * 32 + ic) * 3 + t / 3) * 3 + t % 3;
    }
};
struct Cfg1x1 {     // 1x1, 32->128
    static constexpr int NC = 1, NT = 1, OC = 128;
    __device__ static int widx(int c, int t, int oc, int ic) {
        return oc * 32 + ic;
    }
};

// ----- weight repack: fp32 -> per-lane B-fragment limb layout ---------------
template <typename C>
__device__ inline void repack_one(const float* __restrict__ w,
                                  short* __restrict__ dst, int idx) {
    int s  = idx & 31;
    int oc = (idx >> 5) % C::OC;
    int ct = idx / (32 * C::OC);
    int c = ct / C::NT, t = ct % C::NT;
    float val = w[C::widx(c, t, oc, s)];
    unsigned short h, m, l;
    limb3(val, h, m, l);
    constexpr int NTILE = C::OC / 16;
    int nt = oc >> 4, o = oc & 15, q = s >> 3, j = s & 7;
    int fr = ((q * 16 + o) << 3) + j;
    dst[(((ct * 3 + 0) * NTILE + nt) << 9) + fr] = (short)h;
    dst[(((ct * 3 + 1) * NTILE + nt) << 9) + fr] = (short)m;
    dst[(((ct * 3 + 2) * NTILE + nt) << 9) + fr] = (short)l;
}

__global__ __launch_bounds__(256) void repack_all_k(
    const float* __restrict__ w2, const float* __restrict__ w3,
    const float* __restrict__ r1, const float* __restrict__ r2,
    const float* __restrict__ p1, const float* __restrict__ p2,
    const float* __restrict__ cb, short* __restrict__ base,
    float* __restrict__ encb)
{
    int idx = blockIdx.x * 256 + threadIdx.x;
    if (idx < 131072) { repack_one<CfgConv2>(w2, base + W2_S, idx); return; }
    idx -= 131072;
    if (idx < 147456) { repack_one<CfgConv3>(w3, base + W3_S, idx); return; }
    idx -= 147456;
    if (idx < 36864)  { repack_one<CfgRes>(r1, base + WR1_S, idx); return; }
    idx -= 36864;
    if (idx < 36864)  { repack_one<CfgRes>(r2, base + WR2_S, idx); return; }
    idx -= 36864;
    if (idx < 4096)   { repack_one<Cfg1x1>(p1, base + WP1_S, idx); return; }
    idx -= 4096;
    if (idx < 4096)   { repack_one<Cfg1x1>(p2, base + WP2_S, idx); return; }
    idx -= 4096;
    if (idx < 8192) {  // normalized codebook (same math as old prevq en[])
        int k = idx >> 2, d = idx & 3;
        float c0 = cb[k * 4 + 0], c1 = cb[k * 4 + 1];
        float c2 = cb[k * 4 + 2], c3 = cb[k * 4 + 3];
        float nrm = sqrtf(c0 * c0 + c1 * c1 + c2 * c2 + c3 * c3) + 1e-12f;
        encb[k * 4 + d] = cb[k * 4 + d] / nrm;
    }
}

// ----- pipelined MFMA implicit-GEMM conv (WT_M=4, WT_N=2) — R0 structure ----
template <typename C>
__global__ __launch_bounds__(256, 3) void mfma_conv(
    const float* __restrict__ in, const short* __restrict__ repw,
    const float* __restrict__ bias, float* __restrict__ out, int n0)
{
    constexpr int APLANE = 3 * 66 * 32;        // shorts; dwords 3168
    constexpr int NTILE  = C::OC / 16;
    __shared__ __align__(16) short lA[3 * APLANE];

    int tid = threadIdx.x;
    int lane = tid & 63, wv = tid >> 6;
    int n_img = blockIdx.x >> 6, oy = blockIdx.x & 63;

    // zero halo cells (col 0 and 65, all rows, all limbs)
    for (int idx = tid; idx < 3 * 3 * 2 * 16; idx += 256) {
        int plane = idx / 96;
        int rem = idx % 96;
        int rr = rem / 32;
        int hc = (rem / 16) & 1;
        int d = idx & 15;
        ((unsigned*)lA)[plane * 3168 + (rr * 66 + hc * 65) * 16 + d] = 0;
    }

    v4f acc[4][2] = {};
    int nbase = wv * 2;
    int Xq = tid & 15, icp = tid >> 4, quad = lane >> 4;

    float pv[24];
    auto issue_loads = [&](int c) {
#pragma unroll
        for (int it = 0; it < 12; it++) {
            int r = it >> 2, xg = it & 3;
            int X = xg * 16 + Xq;
            int g0, g1;
            float v0 = 0.f, v1 = 0.f;
            if (C::gaddr(n_img, oy, r, X, icp, c, g0, g1)) {
                v0 = in[g0];
                v1 = in[g1];
            }
            pv[2 * it] = v0; pv[2 * it + 1] = v1;
        }
    };
    auto load_bf = [&](int c, int t, v8s (&dst)[2][3]) {
#pragma unroll
        for (int nt = 0; nt < 2; nt++)
#pragma unroll
            for (int L = 0; L < 3; L++)
                dst[nt][L] = *(const v8s*)(repw +
                    ((((c * C::NT + t) * 3 + L) * NTILE + (nbase + nt)) << 9) +
                    (lane << 3));
    };

    issue_loads(0);

    for (int c = 0; c < C::NC; c++) {
        __syncthreads();   // prev chunk's readers done before lA overwrite
#pragma unroll
        for (int it = 0; it < 12; it++) {
            int r = it >> 2, xg = it & 3;
            int X = xg * 16 + Xq;
            float v0 = pv[2 * it], v1 = pv[2 * it + 1];
            if constexpr (C::RELU_IN) { v0 = fmaxf(v0, 0.f); v1 = fmaxf(v1, 0.f); }
            unsigned short h0, m0, l0, h1, m1, l1;
            limb3(v0, h0, m0, l0);
            limb3(v1, h1, m1, l1);
            int cell = r * 66 + X + 1;
            int f = (cell + (cell >> 2)) & 3;
            int phys = (icp & 3) + 4 * (((icp >> 2) + f) & 3);
            unsigned* pa = (unsigned*)lA + cell * 16 + phys;
            pa[0]        = (unsigned)h0 | ((unsigned)h1 << 16);
            pa[3168]     = (unsigned)m0 | ((unsigned)m1 << 16);
            pa[2 * 3168] = (unsigned)l0 | ((unsigned)l1 << 16);
        }
        __syncthreads();   // lA staged
        if (c + 1 < C::NC) issue_loads(c + 1);   // prefetch next chunk

        v8s bf[2][2][3];
        load_bf(c, 0, bf[0]);
#pragma unroll
        for (int t = 0; t < C::NT; t++) {
            constexpr int NTT = C::NT;
            if (t + 1 < NTT) load_bf(c, t + 1, bf[(t + 1) & 1]);
            int ry, rx;
            C::tap(c, t, ry, rx);
#pragma unroll
            for (int mt = 0; mt < 4; mt++) {
                int x = mt * 16 + (lane & 15);
                int cell = (ry + 1) * 66 + (x + rx + 1);
                int f = (cell + (cell >> 2)) & 3;
                int aa = cell * 32 + (((quad + f) & 3) << 3);
                v8s ah = *(const v8s*)&lA[aa];
                v8s am = *(const v8s*)&lA[APLANE + aa];
                v8s al = *(const v8s*)&lA[2 * APLANE + aa];
#pragma unroll
                for (int nt = 0; nt < 2; nt++) {
                    v4f a0 = acc[mt][nt];
                    a0 = __builtin_amdgcn_mfma_f32_16x16x32_bf16(ah, bf[t & 1][nt][0], a0, 0, 0, 0);
                    a0 = __builtin_amdgcn_mfma_f32_16x16x32_bf16(ah, bf[t & 1][nt][1], a0, 0, 0, 0);
                    a0 = __builtin_amdgcn_mfma_f32_16x16x32_bf16(am, bf[t & 1][nt][0], a0, 0, 0, 0);
                    a0 = __builtin_amdgcn_mfma_f32_16x16x32_bf16(am, bf[t & 1][nt][1], a0, 0, 0, 0);
                    a0 = __builtin_amdgcn_mfma_f32_16x16x32_bf16(ah, bf[t & 1][nt][2], a0, 0, 0, 0);
                    a0 = __builtin_amdgcn_mfma_f32_16x16x32_bf16(al, bf[t & 1][nt][0], a0, 0, 0, 0);
                    acc[mt][nt] = a0;
                }
            }
        }
    }
    // ---- epilogue: pair-plane store, col=lane&15 (oc), row=quad*4+reg (x) --
#pragma unroll
    for (int mt = 0; mt < 4; mt++) {
        int x0 = mt * 16 + quad * 4;
#pragma unroll
        for (int nt = 0; nt < 2; nt++) {
            int oc = (nbase + nt) * 16 + (lane & 15);
            float bv = bias[oc];
            float v0 = acc[mt][nt][0] + bv;
            float v1 = acc[mt][nt][1] + bv;
            float v2 = acc[mt][nt][2] + bv;
            float v3 = acc[mt][nt][3] + bv;
            if constexpr (C::RELU_OUT) {
                v0 = fmaxf(v0, 0.f); v1 = fmaxf(v1, 0.f);
                v2 = fmaxf(v2, 0.f); v3 = fmaxf(v3, 0.f);
            }
            float4 o = make_float4(v0, v1, v2, v3);
            int off = (((n0 + n_img) * 64 + oy) * 64 + (oc >> 1)) * 128 +
                      (oc & 1) * 64 + x0;
            *(float4*)&out[off] = o;
        }
    }
}

// ----- fused residual block, 2 output rows per block (res1: writes h') ------
__global__ __launch_bounds__(256) void mfma_res(
    const float* __restrict__ in, const short* __restrict__ repw,
    const float* __restrict__ b1, const short* __restrict__ repp,
    const float* __restrict__ b2, float* __restrict__ out)
{
    constexpr int PLANE_D = 4 * 66 * 16;   // 4224 dwords per limb plane
    constexpr int PLANE_S = 2 * PLANE_D;   // 8448 shorts
    __shared__ __align__(16) short lA[3 * PLANE_S];   // 50688 B

    int tid = threadIdx.x;
    int lane = tid & 63, wv = tid >> 6;
    int n_img = blockIdx.x >> 5;
    int oy0 = (blockIdx.x & 31) << 1;
    int jrow = wv >> 1, xh = wv & 1;

    for (int idx = tid; idx < 3 * 4 * 2 * 16; idx += 256) {
        int plane = idx / 128;
        int rem = idx % 128;
        int rr = rem / 32;
        int hc = (rem >> 4) & 1;
        int d = idx & 15;
        ((unsigned*)lA)[plane * PLANE_D + (rr * 66 + hc * 65) * 16 + d] = 0;
    }

    v4f acc[2][2] = {};     // [mti][nt]
    int Xq = tid & 15, icp = tid >> 4, quad = lane >> 4;

    float pv[32];
    auto issue_loads = [&](int c) {
#pragma unroll
        for (int it = 0; it < 16; it++) {
            int r = it >> 2, xg = it & 3;
            int X = xg * 16 + Xq;
            int Yg = oy0 + r - 1;
            float v0 = 0.f, v1 = 0.f;
            if (Yg >= 0 && Yg < 64) {
                int g = ((n_img * 64 + Yg) * 64 + (c * 16 + icp)) * 128 + X;
                v0 = in[g];
                v1 = in[g + 64];
            }
            pv[2 * it] = v0; pv[2 * it + 1] = v1;
        }
    };

    issue_loads(0);

    for (int c = 0; c < 4; c++) {
        __syncthreads();
#pragma unroll
        for (int it = 0; it < 16; it++) {
            int r = it >> 2, xg = it & 3;
            int X = xg * 16 + Xq;
            float v0 = fmaxf(pv[2 * it], 0.f);       // relu(h)
            float v1 = fmaxf(pv[2 * it + 1], 0.f);
            unsigned short h0, m0, l0, h1, m1, l1;
            limb3(v0, h0, m0, l0);
            limb3(v1, h1, m1, l1);
            int cell = r * 66 + X + 1;
            int f = (cell + (cell >> 2)) & 3;
            int phys = (icp & 3) + 4 * (((icp >> 2) + f) & 3);
            unsigned* pa = (unsigned*)lA + cell * 16 + phys;
            pa[0]           = (unsigned)h0 | ((unsigned)h1 << 16);
            pa[PLANE_D]     = (unsigned)m0 | ((unsigned)m1 << 16);
            pa[2 * PLANE_D] = (unsigned)l0 | ((unsigned)l1 << 16);
        }
        __syncthreads();
        if (c + 1 < 4) issue_loads(c + 1);

        v8s bf[2][2][3];
        auto load_bf = [&](int t, v8s (&dst)[2][3]) {
#pragma unroll
            for (int nt = 0; nt < 2; nt++)
#pragma unroll
                for (int L = 0; L < 3; L++)
                    dst[nt][L] = *(const v8s*)(repw +
                        ((((c * 9 + t) * 3 + L) * 2 + nt) << 9) + (lane << 3));
        };
        load_bf(0, bf[0]);
#pragma unroll
        for (int t = 0; t < 9; t++) {
            if (t + 1 < 9) load_bf(t + 1, bf[(t + 1) & 1]);
            int ry = t / 3 - 1, rx = t % 3 - 1;
#pragma unroll
            for (int mti = 0; mti < 2; mti++) {
                int x = (xh * 2 + mti) * 16 + (lane & 15);
                int cell = (jrow + ry + 1) * 66 + (x + rx + 1);
                int f = (cell + (cell >> 2)) & 3;
                int aa = cell * 32 + (((quad + f) & 3) << 3);
                v8s ah = *(const v8s*)&lA[aa];
                v8s am = *(const v8s*)&lA[PLANE_S + aa];
                v8s al = *(const v8s*)&lA[2 * PLANE_S + aa];
#pragma unroll
                for (int nt = 0; nt < 2; nt++) {
                    v4f a0 = acc[mti][nt];
                    a0 = __builtin_amdgcn_mfma_f32_16x16x32_bf16(ah, bf[t & 1][nt][0], a0, 0, 0, 0);
                    a0 = __builtin_amdgcn_mfma_f32_16x16x32_bf16(ah, bf[t & 1][nt][1], a0, 0, 0, 0);
                    a0 = __builtin_amdgcn_mfma_f32_16x16x32_bf16(am, bf[t & 1][nt][0], a0, 0, 0, 0);
                    a0 = __builtin_amdgcn_mfma_f32_16x16x32_bf16(am, bf[t & 1][nt][1], a0, 0, 0, 0);
                    a0 = __builtin_amdgcn_mfma_f32_16x16x32_bf16(ah, bf[t & 1][nt][2], a0, 0, 0, 0);
                    a0 = __builtin_amdgcn_mfma_f32_16x16x32_bf16(al, bf[t & 1][nt][0], a0, 0, 0, 0);
                    acc[mti][nt] = a0;
                }
            }
        }
    }

    // ===== stage 2: relu(t+b1) limbs -> LDS (A-frag layout, cell=x) =====
    __syncthreads();
#pragma unroll
    for (int mti = 0; mti < 2; mti++) {
#pragma unroll
        for (int nt = 0; nt < 2; nt++) {
            int ic = nt * 16 + (lane & 15);
            int icp2 = ic >> 1, hilo = ic & 1;
            float bv = b1[ic];
#pragma unroll
            for (int r = 0; r < 4; r++) {
                int x = (xh * 2 + mti) * 16 + quad * 4 + r;
                float v = fmaxf(acc[mti][nt][r] + bv, 0.f);
                unsigned short h, m, l;
                limb3(v, h, m, l);
                int f = (x + (x >> 2)) & 3;
                int phys = (icp2 & 3) + 4 * (((icp2 >> 2) + f) & 3);
                int sa = x * 32 + phys * 2 + hilo;
                lA[jrow * 6144 + sa]        = (short)h;
                lA[jrow * 6144 + 2048 + sa] = (short)m;
                lA[jrow * 6144 + 4096 + sa] = (short)l;
            }
        }
    }
    __syncthreads();

    // GEMM-2 per row: M=64 (x, mt=wv), N=128 (oc2, nt=0..7), K=32
#pragma unroll
    for (int j = 0; j < 2; j++) {
        v4f a2[8] = {};
        int x = wv * 16 + (lane & 15);
        int f = (x + (x >> 2)) & 3;
        int aa = x * 32 + (((quad + f) & 3) << 3);
        v8s ah = *(const v8s*)&lA[j * 6144 + aa];
        v8s am = *(const v8s*)&lA[j * 6144 + 2048 + aa];
        v8s al = *(const v8s*)&lA[j * 6144 + 4096 + aa];
#pragma unroll
        for (int nt = 0; nt < 8; nt++) {
            v8s bh = *(const v8s*)(repp + ((0 * 8 + nt) << 9) + (lane << 3));
            v8s bm = *(const v8s*)(repp + ((1 * 8 + nt) << 9) + (lane << 3));
            v8s bl = *(const v8s*)(repp + ((2 * 8 + nt) << 9) + (lane << 3));
            v4f a0 = a2[nt];
            a0 = __builtin_amdgcn_mfma_f32_16x16x32_bf16(ah, bh, a0, 0, 0, 0);
            a0 = __builtin_amdgcn_mfma_f32_16x16x32_bf16(ah, bm, a0, 0, 0, 0);
            a0 = __builtin_amdgcn_mfma_f32_16x16x32_bf16(am, bh, a0, 0, 0, 0);
            a0 = __builtin_amdgcn_mfma_f32_16x16x32_bf16(am, bm, a0, 0, 0, 0);
            a0 = __builtin_amdgcn_mfma_f32_16x16x32_bf16(ah, bl, a0, 0, 0, 0);
            a0 = __builtin_amdgcn_mfma_f32_16x16x32_bf16(al, bh, a0, 0, 0, 0);
            a2[nt] = a0;
        }
        // epilogue row j: out = h + t2 + b2   (pair-plane layout)
#pragma unroll
        for (int nt = 0; nt < 8; nt++) {
            int oc = nt * 16 + (lane & 15);
            int x0 = wv * 16 + quad * 4;
            int off = ((n_img * 64 + (oy0 + j)) * 64 + (oc >> 1)) * 128 +
                      (oc & 1) * 64 + x0;
            float4 hv = *(const float4*)&in[off];
            float bv = b2[oc];
            float4 o = make_float4(hv.x + a2[nt][0] + bv, hv.y + a2[nt][1] + bv,
                                   hv.z + a2[nt][2] + bv, hv.w + a2[nt][3] + bv);
            *(float4*)&out[off] = o;
        }
    }
}

// ----- fused res2 + 1x1 projection; writes z+bpre to zbuf (1MB) -------------
__global__ __launch_bounds__(256) void mfma_res_vq(
    const float* __restrict__ in, const short* __restrict__ repw,
    const float* __restrict__ b1, const short* __restrict__ repp,
    const float* __restrict__ b2, const float* __restrict__ wpre,
    const float* __restrict__ bpre, float* __restrict__ zbuf)
{
    constexpr int PLANE_D = 4 * 66 * 16;
    constexpr int PLANE_S = 2 * PLANE_D;
    __shared__ __align__(16) short lA[3 * PLANE_S];   // 50688 B

    int tid = threadIdx.x;
    int lane = tid & 63, wv = tid >> 6;
    int n_img = blockIdx.x >> 5;
    int oy0 = (blockIdx.x & 31) << 1;
    int jrow = wv >> 1, xh = wv & 1;

    for (int idx = tid; idx < 3 * 4 * 2 * 16; idx += 256) {
        int plane = idx / 128;
        int rem = idx % 128;
        int rr = rem / 32;
        int hc = (rem >> 4) & 1;
        int d = idx & 15;
        ((unsigned*)lA)[plane * PLANE_D + (rr * 66 + hc * 65) * 16 + d] = 0;
    }

    v4f acc[2][2] = {};
    int Xq = tid & 15, icp = tid >> 4, quad = lane >> 4;

    float pv[32];
    auto issue_loads = [&](int c) {
#pragma unroll
        for (int it = 0; it < 16; it++) {
            int r = it >> 2, xg = it & 3;
            int X = xg * 16 + Xq;
            int Yg = oy0 + r - 1;
            float v0 = 0.f, v1 = 0.f;
            if (Yg >= 0 && Yg < 64) {
                int g = ((n_img * 64 + Yg) * 64 + (c * 16 + icp)) * 128 + X;
                v0 = in[g];
                v1 = in[g + 64];
            }
            pv[2 * it] = v0; pv[2 * it + 1] = v1;
        }
    };

    issue_loads(0);

    for (int c = 0; c < 4; c++) {
        __syncthreads();
#pragma unroll
        for (int it = 0; it < 16; it++) {
            int r = it >> 2, xg = it & 3;
            int X = xg * 16 + Xq;
            float v0 = fmaxf(pv[2 * it], 0.f);
            float v1 = fmaxf(pv[2 * it + 1], 0.f);
            unsigned short h0, m0, l0, h1, m1, l1;
            limb3(v0, h0, m0, l0);
            limb3(v1, h1, m1, l1);
            int cell = r * 66 + X + 1;
            int f = (cell + (cell >> 2)) & 3;
            int phys = (icp & 3) + 4 * (((icp >> 2) + f) & 3);
            unsigned* pa = (unsigned*)lA + cell * 16 + phys;
            pa[0]           = (unsigned)h0 | ((unsigned)h1 << 16);
            pa[PLANE_D]     = (unsigned)m0 | ((unsigned)m1 << 16);
            pa[2 * PLANE_D] = (unsigned)l0 | ((unsigned)l1 << 16);
        }
        __syncthreads();
        if (c + 1 < 4) issue_loads(c + 1);

        v8s bf[2][2][3];
        auto load_bf = [&](int t, v8s (&dst)[2][3]) {
#pragma unroll
            for (int nt = 0; nt < 2; nt++)
#pragma unroll
                for (int L = 0; L < 3; L++)
                    dst[nt][L] = *(const v8s*)(repw +
                        ((((c * 9 + t) * 3 + L) * 2 + nt) << 9) + (lane << 3));
        };
        load_bf(0, bf[0]);
#pragma unroll
        for (int t = 0; t < 9; t++) {
            if (t + 1 < 9) load_bf(t + 1, bf[(t + 1) & 1]);
            int ry = t / 3 - 1, rx = t % 3 - 1;
#pragma unroll
            for (int mti = 0; mti < 2; mti++) {
                int x = (xh * 2 + mti) * 16 + (lane & 15);
                int cell = (jrow + ry + 1) * 66 + (x + rx + 1);
                int f = (cell + (cell >> 2)) & 3;
                int aa = cell * 32 + (((quad + f) & 3) << 3);
                v8s ah = *(const v8s*)&lA[aa];
                v8s am = *(const v8s*)&lA[PLANE_S + aa];
                v8s al = *(const v8s*)&lA[2 * PLANE_S + aa];
#pragma unroll
                for (int nt = 0; nt < 2; nt++) {
                    v4f a0 = acc[mti][nt];
                    a0 = __builtin_amdgcn_mfma_f32_16x16x32_bf16(ah, bf[t & 1][nt][0], a0, 0, 0, 0);
                    a0 = __builtin_amdgcn_mfma_f32_16x16x32_bf16(ah, bf[t & 1][nt][1], a0, 0, 0, 0);
                    a0 = __builtin_amdgcn_mfma_f32_16x16x32_bf16(am, bf[t & 1][nt][0], a0, 0, 0, 0);
                    a0 = __builtin_amdgcn_mfma_f32_16x16x32_bf16(am, bf[t & 1][nt][1], a0, 0, 0, 0);
                    a0 = __builtin_amdgcn_mfma_f32_16x16x32_bf16(ah, bf[t & 1][nt][2], a0, 0, 0, 0);
                    a0 = __builtin_amdgcn_mfma_f32_16x16x32_bf16(al, bf[t & 1][nt][0], a0, 0, 0, 0);
                    acc[mti][nt] = a0;
                }
            }
        }
    }

    // ===== stage 2: relu(t+b1) limbs -> LDS =====
    __syncthreads();
#pragma unroll
    for (int mti = 0; mti < 2; mti++) {
#pragma unroll
        for (int nt = 0; nt < 2; nt++) {
            int ic = nt * 16 + (lane & 15);
            int icp2 = ic >> 1, hilo = ic & 1;
            float bv = b1[ic];
#pragma unroll
            for (int r = 0; r < 4; r++) {
                int x = (xh * 2 + mti) * 16 + quad * 4 + r;
                float v = fmaxf(acc[mti][nt][r] + bv, 0.f);
                unsigned short h, m, l;
                limb3(v, h, m, l);
                int f = (x + (x >> 2)) & 3;
                int phys = (icp2 & 3) + 4 * (((icp2 >> 2) + f) & 3);
                int sa = x * 32 + phys * 2 + hilo;
                lA[jrow * 6144 + sa]        = (short)h;
                lA[jrow * 6144 + 2048 + sa] = (short)m;
                lA[jrow * 6144 + 4096 + sa] = (short)l;
            }
        }
    }
    __syncthreads();

    // per-thread wpre cache: wp[nt][d] = wpre[d*128 + nt*16 + lane15]
    float wp[8][4];
#pragma unroll
    for (int nt = 0; nt < 8; nt++)
#pragma unroll
        for (int d = 0; d < 4; d++)
            wp[nt][d] = wpre[d * 128 + nt * 16 + (lane & 15)];

    // GEMM-2 + z accumulation per row; butterfly; write z+bpre to zbuf
#pragma unroll
    for (int j = 0; j < 2; j++) {
        v4f a2[8] = {};
        int x = wv * 16 + (lane & 15);
        int f = (x + (x >> 2)) & 3;
        int aa = x * 32 + (((quad + f) & 3) << 3);
        v8s ah = *(const v8s*)&lA[j * 6144 + aa];
        v8s am = *(const v8s*)&lA[j * 6144 + 2048 + aa];
        v8s al = *(const v8s*)&lA[j * 6144 + 4096 + aa];
#pragma unroll
        for (int nt = 0; nt < 8; nt++) {
            v8s bh = *(const v8s*)(repp + ((0 * 8 + nt) << 9) + (lane << 3));
            v8s bm = *(const v8s*)(repp + ((1 * 8 + nt) << 9) + (lane << 3));
            v8s bl = *(const v8s*)(repp + ((2 * 8 + nt) << 9) + (lane << 3));
            v4f a0 = a2[nt];
            a0 = __builtin_amdgcn_mfma_f32_16x16x32_bf16(ah, bh, a0, 0, 0, 0);
            a0 = __builtin_amdgcn_mfma_f32_16x16x32_bf16(ah, bm, a0, 0, 0, 0);
            a0 = __builtin_amdgcn_mfma_f32_16x16x32_bf16(am, bh, a0, 0, 0, 0);
            a0 = __builtin_amdgcn_mfma_f32_16x16x32_bf16(am, bm, a0, 0, 0, 0);
            a0 = __builtin_amdgcn_mfma_f32_16x16x32_bf16(ah, bl, a0, 0, 0, 0);
            a0 = __builtin_amdgcn_mfma_f32_16x16x32_bf16(al, bh, a0, 0, 0, 0);
            a2[nt] = a0;
        }
        // h' = h + t2 + b2 stays in registers; accumulate partial z
        float z[4][4];   // [r][d], compile-time indexed only
#pragma unroll
        for (int r = 0; r < 4; r++)
#pragma unroll
            for (int d = 0; d < 4; d++) z[r][d] = 0.f;
#pragma unroll
        for (int nt = 0; nt < 8; nt++) {
            int oc = nt * 16 + (lane & 15);
            int x0 = wv * 16 + quad * 4;
            int off = ((n_img * 64 + (oy0 + j)) * 64 + (oc >> 1)) * 128 +
                      (oc & 1) * 64 + x0;
            float4 hv = *(const float4*)&in[off];
            float bv = b2[oc];
            float o0 = fmaxf(hv.x + a2[nt][0] + bv, 0.f);
            float o1 = fmaxf(hv.y + a2[nt][1] + bv, 0.f);
            float o2 = fmaxf(hv.z + a2[nt][2] + bv, 0.f);
            float o3 = fmaxf(hv.w + a2[nt][3] + bv, 0.f);
#pragma unroll
            for (int d = 0; d < 4; d++) {
                z[0][d] = fmaf(o0, wp[nt][d], z[0][d]);
                z[1][d] = fmaf(o1, wp[nt][d], z[1][d]);
                z[2][d] = fmaf(o2, wp[nt][d], z[2][d]);
                z[3][d] = fmaf(o3, wp[nt][d], z[3][d]);
            }
        }
        // butterfly over the 16 lanes of this quad group (channels)
#pragma unroll
        for (int mask = 1; mask < 16; mask <<= 1)
#pragma unroll
            for (int r = 0; r < 4; r++)
#pragma unroll
                for (int d = 0; d < 4; d++)
                    z[r][d] += __shfl_xor(z[r][d], mask);
        // lane l15==r*4+d writes position (wv*16+quad*4+r), dim d -> coalesced
        int l15 = lane & 15;
#pragma unroll
        for (int r = 0; r < 4; r++)
#pragma unroll
            for (int d = 0; d < 4; d++)
                if (l15 == r * 4 + d)
                    zbuf[(((n_img * 64 + oy0 + j) * 64) + wv * 16 + quad * 4 + r) * 4 + d]
                        = z[r][d] + bpre[d];
    }
}

// ----- standalone argmax scan: codebook in LDS, wave-uniform k --------------
// 1024 blocks x 256. Block handles 64 positions; wave w scans k in
// [w*512,(w+1)*512) with lane = position (z register-resident, LDS read is
// same-address broadcast). 4 ILP chains per wave; (max s, tie min idx)
// semilattice merge == exact global first-max.
__global__ __launch_bounds__(256) void scan_vq(
    const float* __restrict__ zbuf, const float* __restrict__ encb,
    const float* __restrict__ cb, float* __restrict__ out)
{
    __shared__ __align__(16) float en[2048 * 4];
    __shared__ float cwS[4][64];
    __shared__ int   cwI[4][64];
    for (int i = threadIdx.x; i < 2048; i += 256)
        ((float4*)en)[i] = ((const float4*)encb)[i];
    __syncthreads();

    int lane = threadIdx.x & 63, w = threadIdx.x >> 6;
    int gpos = blockIdx.x * 64 + lane;
    float4 zv = ((const float4*)zbuf)[gpos];

    int kb = w * 512;
    float b0 = -1e30f, b1 = -1e30f, b2 = -1e30f, b3 = -1e30f;
    int i0 = kb, i1 = kb + 1, i2 = kb + 2, i3 = kb + 3;
    for (int i = 0; i < 512; i += 4) {
        float4 e0 = ((const float4*)en)[kb + i];
        float4 e1 = ((const float4*)en)[kb + i + 1];
        float4 e2 = ((const float4*)en)[kb + i + 2];
        float4 e3 = ((const float4*)en)[kb + i + 3];
        float s0 = zv.x * e0.x + zv.y * e0.y + zv.z * e0.z + zv.w * e0.w;
        float s1 = zv.x * e1.x + zv.y * e1.y + zv.z * e1.z + zv.w * e1.w;
        float s2 = zv.x * e2.x + zv.y * e2.y + zv.z * e2.z + zv.w * e2.w;
        float s3 = zv.x * e3.x + zv.y * e3.y + zv.z * e3.z + zv.w * e3.w;
        if (s0 > b0) { b0 = s0; i0 = kb + i; }
        if (s1 > b1) { b1 = s1; i1 = kb + i + 1; }
        if (s2 > b2) { b2 = s2; i2 = kb + i + 2; }
        if (s3 > b3) { b3 = s3; i3 = kb + i + 3; }
    }
    // merge 4 chains: max s, tie -> min idx (exact; ranges interleave mod 4)
    float best = b0; int bidx = i0;
    if (b1 > best || (b1 == best && i1 < bidx)) { best = b1; bidx = i1; }
    if (b2 > best || (b2 == best && i2 < bidx)) { best = b2; bidx = i2; }
    if (b3 > best || (b3 == best && i3 < bidx)) { best = b3; bidx = i3; }
    cwS[w][lane] = best;
    cwI[w][lane] = bidx;
    __syncthreads();
    if (w == 0) {
#pragma unroll
        for (int ww = 1; ww < 4; ww++) {
            float ob = cwS[ww][lane];
            int   oi = cwI[ww][lane];
            if (ob > best || (ob == best && oi < bidx)) { best = ob; bidx = oi; }
        }
        int n = gpos >> 12, pos = gpos & 4095;
#pragma unroll
        for (int d = 0; d < 4; d++)
            out[(n * 4 + d) * 4096 + pos] = cb[bidx * 4 + d];
    }
}

// ----- conv1: [8,1,256,256] -> phase-split pair-plane, relu (fp32) ----------
__global__ __launch_bounds__(256) void conv1_k(
    const float* __restrict__ x, const float* __restrict__ w,
    const float* __restrict__ b, float* __restrict__ out)
{
    int tid = blockIdx.x * 256 + threadIdx.x;     // 131072
    int n   = tid >> 14;
    int rem = tid & 16383;
    int oy  = rem >> 7;
    int ox  = rem & 127;
    int iy0 = oy * 2 - 1, ix0 = ox * 2 - 1;
    const float* xb = x + n * 65536;
    float v[16];
#pragma unroll
    for (int ky = 0; ky < 4; ky++) {
#pragma unroll
        for (int kx = 0; kx < 4; kx++) {
            int iy = iy0 + ky, ix = ix0 + kx;
            bool ok = (iy >= 0) & (iy < 256) & (ix >= 0) & (ix < 256);
            v[ky * 4 + kx] = ok ? xb[iy * 256 + ix] : 0.f;
        }
    }
    int py = oy & 1, y2 = oy >> 1, px = ox & 1, x2 = ox >> 1;
    int obase = (((n * 4 + py * 2 + px) * 64 + y2) * 32) * 128 + x2;
    for (int oc = 0; oc < 64; oc++) {
        float acc = b[oc];
        const float* wp = w + oc * 16;
#pragma unroll
        for (int k = 0; k < 16; k++) acc = fmaf(v[k], wp[k], acc);
        out[obase + (oc >> 1) * 128 + (oc & 1) * 64] = fmaxf(acc, 0.f);
    }
}

extern "C" void kernel_launch(void* const* d_in, const int* in_sizes, int n_in,
                              void* d_out, int out_size, void* d_ws, size_t ws_size,
                              hipStream_t stream)
{
    const float* x    = (const float*)d_in[0];
    const float* w1   = (const float*)d_in[1];
    const float* b1   = (const float*)d_in[2];
    const float* w2   = (const float*)d_in[3];
    const float* b2   = (const float*)d_in[4];
    const float* w3   = (const float*)d_in[5];
    const float* b3   = (const float*)d_in[6];
    const float* r1w1 = (const float*)d_in[7];
    const float* r1b1 = (const float*)d_in[8];
    const float* r1w2 = (const float*)d_in[9];
    const float* r1b2 = (const float*)d_in[10];
    const float* r2w1 = (const float*)d_in[11];
    const float* r2b1 = (const float*)d_in[12];
    const float* r2w2 = (const float*)d_in[13];
    const float* r2b2 = (const float*)d_in[14];
    const float* wpre = (const float*)d_in[15];
    const float* bpre = (const float*)d_in[16];
    const float* cb   = (const float*)d_in[17];
    float* out = (float*)d_out;

    float* ws   = (float*)d_ws;
    short* wsS  = (short*)d_ws;
    float* encb = ws + ENCB_F;
    float* zbuf = ws + ZB_F;
    float* B = ws + B_OFF;
    float* A = ws + A_OFF;

    // merged repack for all 6 weight tensors + normalized codebook
    repack_all_k<<<1440, 256, 0, stream>>>(w2, w3, r1w1, r2w1, r1w2, r2w2,
                                           cb, wsS, encb);

    // front end, batch split in halves ping-ponging through A
    conv1_k<<<512, 256, 0, stream>>>(x,               w1, b1, A);
    mfma_conv<CfgConv2><<<512, 256, 0, stream>>>(A, wsS + W2_S, b2, B, 0);
    conv1_k<<<512, 256, 0, stream>>>(x + 8 * 65536,   w1, b1, A);
    mfma_conv<CfgConv2><<<512, 256, 0, stream>>>(A, wsS + W2_S, b2, B, 8);

    // conv3: B -> h @ A
    mfma_conv<CfgConv3><<<1024, 256, 0, stream>>>(B, wsS + W3_S, b3, A, 0);

    // res1: A -> B
    mfma_res<<<512, 256, 0, stream>>>(A, wsS + WR1_S, r1b1, wsS + WP1_S, r1b2, B);
    // res2 + projection fused: B -> zbuf (h' never touches HBM)
    mfma_res_vq<<<512, 256, 0, stream>>>(B, wsS + WR2_S, r2b1, wsS + WP2_S,
                                         r2b2, wpre, bpre, zbuf);
    // argmax scan: zbuf (1MB) + LDS codebook -> out
    scan_vq<<<1024, 256, 0, stream>>>(zbuf, encb, cb, out);
}